// Round 1
// 82.855 us; speedup vs baseline: 1.0587x; 1.0587x over previous
//
#include <hip/hip_runtime.h>
#include <hip/hip_fp16.h>

// NonAutoregressiveDecoder: K=1024, H=128, fp32 I/O.
// out = (coords_pred [1024,2], adj_logits [1024,1024]) flat-concat.

#define KN 1024
#define HN 128

typedef float  floatx4 __attribute__((ext_vector_type(4)));
typedef _Float16 half8v __attribute__((ext_vector_type(8)));

// lean f32 GELU (tanh form, log2e folded): x * sigmoid(1.5958x + 0.07135x^3)
//   = x / (1 + exp2(x * (-2.3022087 - 0.1029434 x^2)))
__device__ __forceinline__ float gelu_f(float x) {
    float x2 = x * x;
    float t  = fmaf(x2, -0.1029434f, -2.3022087f);
    float e  = __builtin_amdgcn_exp2f(x * t);
    return x * __builtin_amdgcn_rcpf(e + 1.0f);
}

// packed-f16 GELU on 2 elements held in a uint
__device__ __forceinline__ unsigned int gelu2u(unsigned int xu) {
    __half2 x  = __builtin_bit_cast(__half2, xu);
    __half2 x2 = __hmul2(x, x);
    __half2 t  = __hfma2(x2, __float2half2_rn(-0.1029434f),
                             __float2half2_rn(-2.3022087f));
    __half2 e  = h2exp2(__hmul2(x, t));
    __half2 r  = h2rcp(__hadd2(e, __float2half2_rn(1.0f)));
    return __builtin_bit_cast(unsigned int, __hmul2(x, r));
}

// ---------------- Kernel A: pi' = z@eW1[:H]+eb1 (f16), pj = z@eW1[H:] (f16),
//                  coords -> d_out, w2T (f16 transpose of eW2) -------------
__global__ __launch_bounds__(256) void prep_kernel(
    const float* __restrict__ z,   const float* __restrict__ cW1,
    const float* __restrict__ cb1, const float* __restrict__ cW2,
    const float* __restrict__ cb2, const float* __restrict__ eW1,
    const float* __restrict__ eb1, const float* __restrict__ eW2,
    _Float16* __restrict__ pi_h,   _Float16* __restrict__ pj_h,
    _Float16* __restrict__ w2T,    float* __restrict__ coords /* = d_out */) {
    __shared__ float z8[8][128];
    __shared__ float c1s[8][64];
    const int tid = threadIdx.x;
    const int r0  = blockIdx.x * 8;

    // w2T fill: blocks 0..31, 256 elems each. w2T[col][k] = eW2[k][col]
    if (blockIdx.x < 32) {
        int e = blockIdx.x * 256 + tid;          // e = col*128 + k
        w2T[e] = (_Float16)eW2[(e & 127) * 64 + (e >> 7)];
    }

#pragma unroll
    for (int s = 0; s < 4; ++s) {
        int e = tid + 256 * s;
        z8[e >> 7][e & 127] = z[r0 * HN + e];
    }
    __syncthreads();

    const int col = tid & 127, which = tid >> 7;
    const float* w = eW1 + which * HN * HN + col;
    float acc8[8] = {0.f, 0.f, 0.f, 0.f, 0.f, 0.f, 0.f, 0.f};
    for (int k = 0; k < HN; ++k) {
        float wv = w[k * HN];
#pragma unroll
        for (int r = 0; r < 8; ++r) acc8[r] = fmaf(z8[r][k], wv, acc8[r]);
    }
    if (which == 0) {
        float b = eb1[col];
#pragma unroll
        for (int r = 0; r < 8; ++r)
            pi_h[(r0 + r) * HN + col] = (_Float16)(acc8[r] + b);
    } else {
#pragma unroll
        for (int r = 0; r < 8; ++r)
            pj_h[(r0 + r) * HN + col] = (_Float16)acc8[r];
    }

    // coords: c1 = gelu(z @ cW1 + cb1), coords = c1 @ cW2 + cb2
#pragma unroll
    for (int s = 0; s < 2; ++s) {
        int task = tid + 256 * s;          // 512 tasks = 8 rows x 64 mids
        int row = task >> 6, mid = task & 63;
        float a = cb1[mid];
        for (int k = 0; k < HN; ++k) a = fmaf(z8[row][k], cW1[k * 64 + mid], a);
        c1s[row][mid] = gelu_f(a);
    }
    __syncthreads();
    if (tid < 16) {
        int row = tid >> 1, o = tid & 1;
        float a = cb2[o];
#pragma unroll 8
        for (int m = 0; m < 64; ++m) a = fmaf(c1s[row][m], cW2[m * 2 + o], a);
        coords[(r0 + row) * 2 + o] = a;
    }
}

// ---------------- Kernel B: fused h1->h2->adj_raw over a 32x16 (i,j) tile ----
// 512 threads (8 waves), each wave does 4 i-rows. w2 fragments live in LDS
// (not registers/AGPRs) so the wave fits <=72 VGPR -> 7 waves/SIMD occupancy.
// All LDS buffers XOR-swizzled: dword_idx ^= (row&7)<<2  (byte ^= (row&7)<<4)
// so 16-row column-slice ds_read_b128 is ~2-way (free) instead of 16-way.
__global__ __launch_bounds__(512, 7) void edge_kernel(
    const _Float16* __restrict__ pi_h, const _Float16* __restrict__ pj_h,
    const _Float16* __restrict__ w2T,  const float* __restrict__ eb2,
    const float* __restrict__ eW3,     const float* __restrict__ eb3,
    float* __restrict__ out_adj) {
    __shared__ __align__(16) unsigned int pi_s[32 * 64];  // 8 KB  [32 rows][64 dw]
    __shared__ __align__(16) unsigned int pj_s[16 * 64];  // 4 KB  [16 rows][64 dw]
    __shared__ __align__(16) unsigned int w2_s[64 * 64];  // 16 KB [64 dims][64 dw]
    const int i0 = blockIdx.y * 32, j0 = blockIdx.x * 16;
    const int tid = threadIdx.x;

    const unsigned int* piu = (const unsigned int*)pi_h;   // [1024][64]
    const unsigned int* pju = (const unsigned int*)pj_h;
    const unsigned int* w2u = (const unsigned int*)w2T;    // [64][64]

#pragma unroll
    for (int s = 0; s < 4; ++s) {
        int e = tid + 512 * s;            // 0..2047
        int r = e >> 6;
        pi_s[e ^ ((r & 7) << 2)] = piu[(i0 + r) * 64 + (e & 63)];
    }
#pragma unroll
    for (int s = 0; s < 2; ++s) {
        int e = tid + 512 * s;            // 0..1023
        int r = e >> 6;
        pj_s[e ^ ((r & 7) << 2)] = pju[(j0 + r) * 64 + (e & 63)];
    }
#pragma unroll
    for (int s = 0; s < 8; ++s) {
        int e = tid + 512 * s;            // 0..4095
        int r = e >> 6;
        w2_s[e ^ ((r & 7) << 2)] = w2u[e];
    }

    const int lane = tid & 63;
    const int wave = tid >> 6;          // 0..7
    const int lrow = lane & 15;         // A-row (j) / B-col (h2 dim) within 16
    const int lhi  = lane >> 4;         // k-block / C-row-group
    const int lhi4 = lhi << 2;
    const int swzJ = (lrow & 7) << 2;

    const unsigned int* pjrow  = &pj_s[lrow << 6];
    const unsigned int* w2base = &w2_s[lrow << 6];

    float eb2_l[4], w3_l[4];
#pragma unroll
    for (int c = 0; c < 4; ++c) {
        eb2_l[c] = eb2[c * 16 + lrow];
        w3_l[c]  = eW3[c * 16 + lrow];
    }
    const float b3 = eb3[0];
    __syncthreads();

#pragma unroll
    for (int t = 0; t < 4; ++t) {
        const int iL = (wave << 2) + t;             // 0..31
        const unsigned int* pirow = &pi_s[iL << 6];
        const int swzI = (iL & 7) << 2;

        floatx4 acc[4];
#pragma unroll
        for (int c = 0; c < 4; ++c) acc[c] = (floatx4){0.f, 0.f, 0.f, 0.f};

#pragma unroll
        for (int q = 0; q < 4; ++q) {
            const int ko = (q << 4) + lhi4;         // dword offset within row
            half8v a = *reinterpret_cast<const half8v*>(&pirow[ko ^ swzI]);
            half8v b = *reinterpret_cast<const half8v*>(&pjrow[ko ^ swzJ]);
            uint4 su = __builtin_bit_cast(uint4, a + b);   // v_pk_add_f16
            uint4 gu;
            gu.x = gelu2u(su.x);
            gu.y = gelu2u(su.y);
            gu.z = gelu2u(su.z);
            gu.w = gelu2u(su.w);
            half8v af = __builtin_bit_cast(half8v, gu);
            const int kw = ko ^ swzJ;               // w2 rows share lrow&7 swizzle
#pragma unroll
            for (int c = 0; c < 4; ++c) {
                half8v bf = *reinterpret_cast<const half8v*>(
                    &w2base[(c << 10) + kw]);       // row c*16+lrow, same offset
                acc[c] = __builtin_amdgcn_mfma_f32_16x16x32_f16(
                    af, bf, acc[c], 0, 0, 0);
            }
        }

        // epilogue: h2 = gelu(acc + eb2); adj = h2 . eW3 + eb3
        float tv[4];
#pragma unroll
        for (int m = 0; m < 4; ++m) {
            float s = 0.f;
#pragma unroll
            for (int c = 0; c < 4; ++c)
                s = fmaf(gelu_f(acc[c][m] + eb2_l[c]), w3_l[c], s);
            s += __shfl_xor(s, 1);
            s += __shfl_xor(s, 2);
            s += __shfl_xor(s, 4);
            s += __shfl_xor(s, 8);
            tv[m] = s + b3;
        }
        if (lrow == 0) {
            float4 v = make_float4(tv[0], tv[1], tv[2], tv[3]);
            *reinterpret_cast<float4*>(
                &out_adj[(size_t)(i0 + iL) * KN + j0 + lhi4]) = v;
        }
    }
}

// ---------------- Kernel C: in-place symmetrize ------------------------------
__global__ __launch_bounds__(256) void sym_kernel(float* __restrict__ adj) {
    int idx = blockIdx.x * 256 + threadIdx.x;
    int i = idx >> 10, j = idx & 1023;
    if (j < i) return;
    float a = adj[i * KN + j];
    float b = adj[j * KN + i];
    float m = 0.5f * (a + b);
    adj[i * KN + j] = m;
    adj[j * KN + i] = m;
}

extern "C" void kernel_launch(void* const* d_in, const int* in_sizes, int n_in,
                              void* d_out, int out_size, void* d_ws, size_t ws_size,
                              hipStream_t stream) {
    const float* z   = (const float*)d_in[0];
    const float* cW1 = (const float*)d_in[1];
    const float* cb1 = (const float*)d_in[2];
    const float* cW2 = (const float*)d_in[3];
    const float* cb2 = (const float*)d_in[4];
    const float* eW1 = (const float*)d_in[5];
    const float* eb1 = (const float*)d_in[6];
    const float* eW2 = (const float*)d_in[7];
    const float* eb2 = (const float*)d_in[8];
    const float* eW3 = (const float*)d_in[9];
    const float* eb3 = (const float*)d_in[10];

    float* out = (float*)d_out;
    _Float16* pi_h = (_Float16*)d_ws;            // [1024][128] f16
    _Float16* pj_h = pi_h + KN * HN;             // [1024][128] f16
    _Float16* w2T  = pj_h + KN * HN;             // [64][128]  f16 (eW2^T)

    prep_kernel<<<128, 256, 0, stream>>>(z, cW1, cb1, cW2, cb2, eW1, eb1, eW2,
                                         pi_h, pj_h, w2T, out);

    dim3 gridB(64, 32);   // x: 16-wide j tiles, y: 32-tall i tiles
    edge_kernel<<<gridB, 512, 0, stream>>>(pi_h, pj_h, w2T, eb2, eW3, eb3,
                                           out + 2048);

    sym_kernel<<<4096, 256, 0, stream>>>(out + 2048);
}